// Round 5
// baseline (248.226 us; speedup 1.0000x reference)
//
#include <hip/hip_runtime.h>

// EMA scan: out[:,0,:] = x[:,0,:]; out[:,t,:] = 0.1*x[:,t,:] + 0.9*out[:,t-1,:]
// x: (16, 4096, 512) fp32.
//
// Chunked-scan: recurrence forgets at 0.9^W; each chunk rebuilds its carry
// with a W=64 warm-up from zero (measured absmax 7.8e-3 at R3, threshold 7.6e-2).
// CONSTRAINT: L >= W so t0 - W >= 0 for all chunks >= 1 (R4's L=32 read OOB
// before the buffer for b=0 -> core dump).
// R3 post-mortem: FETCH == input exactly (L2/L3 absorb all warm-up re-reads),
// BW stuck at 2.8 TB/s independent of occupancy -> per-wave vmcnt full drains
// (one register batch recycled; NT store acks from HBM) serialize each wave.
// R5 = R3 shape (L=64, 512 blocks, 8 waves/CU) changing ONLY the pipeline:
// ping-pong register double-buffer (staged vmcnt waits) + plain stores.

typedef float vf4 __attribute__((ext_vector_type(4)));

constexpr int B = 16;
constexpr int T = 4096;
constexpr int D = 512;
constexpr int DV = D / 4;      // 128 float4 columns per (b, t) row
constexpr int L = 64;          // chunk length along T (must be >= W)
constexpr int C = T / L;       // 64 chunks
constexpr int W = 64;          // warm-up steps (0.9^64 ~ 1.2e-3)
constexpr int UNR = 8;         // loads per batch
constexpr int NBW = W / UNR;   // 8 warm-up batches
constexpr int NBM = L / UNR;   // 8 main batches

static_assert(L >= W, "warm-up must not cross below t=0 for chunk 1");

__global__ __launch_bounds__(256)
void ema_chunked_kernel(const vf4* __restrict__ X, vf4* __restrict__ O) {
    const int g     = blockIdx.x * 256 + threadIdx.x;
    const int dvec  = g & (DV - 1);          // wave-contiguous -> coalesced 1KB/instr
    const int chunk = (g >> 7) & (C - 1);    // wave-uniform
    const int b     = g >> 13;               // DV*C = 8192 = 1<<13

    const float a  = 0.1f;
    const float bb = 0.9f;

    const int base = b * (T * DV) + dvec;
    const int t0   = chunk * L;

    vf4 y;
    vf4 buf[2][UNR];

    if (chunk == 0) {
        // y_init = x0: main-loop step at t=0 gives 0.1*x0 + 0.9*x0 = x0 exactly.
        y = X[base];
    } else {
        y = (vf4)(0.f);
        const vf4* xp = X + base + (t0 - W) * DV;
        #pragma unroll
        for (int j = 0; j < UNR; ++j) buf[0][j] = xp[j * DV];
        #pragma unroll
        for (int kb = 0; kb < NBW; ++kb) {
            if (kb + 1 < NBW) {
                #pragma unroll
                for (int j = 0; j < UNR; ++j)
                    buf[(kb + 1) & 1][j] = xp[((kb + 1) * UNR + j) * DV];
            }
            #pragma unroll
            for (int j = 0; j < UNR; ++j)
                y = bb * y + a * buf[kb & 1][j];
        }
    }

    const vf4* xp = X + base + t0 * DV;
    vf4*       op = O + base + t0 * DV;
    #pragma unroll
    for (int j = 0; j < UNR; ++j) buf[0][j] = xp[j * DV];
    #pragma unroll
    for (int kb = 0; kb < NBM; ++kb) {
        if (kb + 1 < NBM) {
            #pragma unroll
            for (int j = 0; j < UNR; ++j)
                buf[(kb + 1) & 1][j] = xp[((kb + 1) * UNR + j) * DV];
        }
        #pragma unroll
        for (int j = 0; j < UNR; ++j) {
            y = bb * y + a * buf[kb & 1][j];
            op[(kb * UNR + j) * DV] = y;
        }
    }
}

extern "C" void kernel_launch(void* const* d_in, const int* in_sizes, int n_in,
                              void* d_out, int out_size, void* d_ws, size_t ws_size,
                              hipStream_t stream) {
    const vf4* X = (const vf4*)d_in[0];
    vf4*       O = (vf4*)d_out;

    const int total_threads = B * C * DV;    // 131072
    const int block = 256;
    const int grid  = total_threads / block; // 512 blocks -> 8 waves/CU
    ema_chunked_kernel<<<grid, block, 0, stream>>>(X, O);
}